// Round 10
// baseline (6751.414 us; speedup 1.0000x reference)
//
#include <hip/hip_runtime.h>
#include <math.h>

#define D_IN   512
#define HID    1024
#define SEQ    512
#define NBATCH 64
#define K3     3072
#define KTOT   1536
#define WB_ELEMS (K3 * KTOT)
#define NBLK   256
#define XP_ROWS (NBATCH * SEQ)                     // 32768 (b*512+t)
#define XP_BYTES ((size_t)XP_ROWS * K3 * 4)        // 402.7 MB

typedef __attribute__((ext_vector_type(8))) short short8;
typedef __attribute__((ext_vector_type(4))) float f32x4;

#define MFMA(a, b, c) __builtin_amdgcn_mfma_f32_16x16x32_bf16((a), (b), (c), 0, 0, 0)

// ---------------- build fused transposed weight planes (hi/lo bf16) ----------------
__global__ __launch_bounds__(256) void build_wt(const float* __restrict__ Win,
                                                const float* __restrict__ Wh,
                                                __bf16* __restrict__ WBh,
                                                __bf16* __restrict__ WBl) {
    int idx = blockIdx.x * 256 + threadIdx.x;
    if (idx >= WB_ELEMS) return;
    int k   = idx % KTOT;
    int col = idx / KTOT;
    float v = (k < D_IN) ? Win[(size_t)k * K3 + col]
                         : Wh[(size_t)(k - D_IN) * K3 + col];
    __bf16 hi = (__bf16)v;
    WBh[idx] = hi;
    WBl[idx] = (__bf16)(v - (float)hi);
}

__device__ __forceinline__ void cvt8(const f32x4& v0, const f32x4& v1,
                                     short8& ahi, short8& alo) {
    float af[8] = {v0[0], v0[1], v0[2], v0[3], v1[0], v1[1], v1[2], v1[3]};
    #pragma unroll
    for (int j = 0; j < 8; ++j) {
        __bf16 hb = (__bf16)af[j];
        __bf16 lb = (__bf16)(af[j] - (float)hb);
        ahi[j] = __builtin_bit_cast(short, hb);
        alo[j] = __builtin_bit_cast(short, lb);
    }
}

// ---------------- one-shot x-projection: xp[r][3072] = x[r] @ Win + bin ----------------
// r = b*512 + t (matches x (B,S,D) layout). Grid (2048, 64), 256 thr (4 waves,
// K-split 128). Round-2-proven tile: 16 rows x {ct, 1024+ct, 2048+ct}.
__global__ __launch_bounds__(256) void xproj_all(const float* __restrict__ x,
                                                 const float* __restrict__ bin,
                                                 const __bf16* __restrict__ WBh,
                                                 const __bf16* __restrict__ WBl,
                                                 float* __restrict__ xp) {
    __shared__ float red[4][3][4][64];   // 12 KB
    const int tid = threadIdx.x;
    const int l   = tid & 63;
    const int w   = tid >> 6;
    const int mt  = blockIdx.x;          // row tile
    const int cn  = blockIdx.y;          // col tile
    const int rl  = mt * 16 + (l & 15);
    const int koff = (l >> 4) * 8;
    const int ct  = cn * 16 + (l & 15);

    f32x4 aZ = {0.f,0.f,0.f,0.f}, aR = {0.f,0.f,0.f,0.f}, aN = {0.f,0.f,0.f,0.f};
    const int kw0 = w * 128;
    #pragma unroll
    for (int s = 0; s < 4; ++s) {
        const int ks = kw0 + 32 * s;
        const float* ap = x + (size_t)rl * D_IN + ks + koff;
        f32x4 v0 = *(const f32x4*)ap;
        f32x4 v1 = *(const f32x4*)(ap + 4);
        short8 ahi, alo;
        cvt8(v0, v1, ahi, alo);
        const size_t o0 = (size_t)ct * KTOT + ks + koff;
        const size_t o1 = o0 + (size_t)HID * KTOT;
        const size_t o2 = o1 + (size_t)HID * KTOT;
        short8 bzh = *(const short8*)(WBh + o0);
        short8 bzl = *(const short8*)(WBl + o0);
        short8 brh = *(const short8*)(WBh + o1);
        short8 brl = *(const short8*)(WBl + o1);
        short8 bnh = *(const short8*)(WBh + o2);
        short8 bnl = *(const short8*)(WBl + o2);
        aZ = MFMA(ahi, bzh, aZ); aZ = MFMA(ahi, bzl, aZ); aZ = MFMA(alo, bzh, aZ);
        aR = MFMA(ahi, brh, aR); aR = MFMA(ahi, brl, aR); aR = MFMA(alo, brh, aR);
        aN = MFMA(ahi, bnh, aN); aN = MFMA(ahi, bnl, aN); aN = MFMA(alo, bnh, aN);
    }
    #pragma unroll
    for (int r = 0; r < 4; ++r) {
        red[w][0][r][l] = aZ[r];
        red[w][1][r][l] = aR[r];
        red[w][2][r][l] = aN[r];
    }
    __syncthreads();
    const int r2 = tid >> 6;
    const int l2 = tid & 63;
    float sz = 0.f, sr = 0.f, sn = 0.f;
    #pragma unroll
    for (int wv = 0; wv < 4; ++wv) {
        sz += red[wv][0][r2][l2];
        sr += red[wv][1][r2][l2];
        sn += red[wv][2][r2][l2];
    }
    const int ro  = mt * 16 + (l2 >> 4) * 4 + r2;   // C layout (m89)
    const int ct2 = cn * 16 + (l2 & 15);
    const size_t base = (size_t)ro * K3 + ct2;
    xp[base]            = sz + bin[ct2];
    xp[base + HID]      = sr + bin[HID + ct2];
    xp[base + 2 * HID]  = sn + bin[2 * HID + ct2];
}

// ---------------- recurrence-only persistent kernel ----------------
// Grid 256 x 512 (8 h-waves). Block (mq=j&3, nb=xcd+8*(j>>2)), xcd=bid&7.
// Wave w: h-part K slice [512+128w, +128), weights reg/AGPR-resident.
// One __syncthreads per step (red double-buffered; WAR safe: waves 0-3 only
// reach sync(t+1) after epilogue(t)). Dataflow counters as round 9.
__global__ __attribute__((amdgpu_waves_per_eu(2, 2)))
__launch_bounds__(512) void gru_persist2(
        const float* __restrict__ xp,
        const __bf16* __restrict__ WBh, const __bf16* __restrict__ WBl,
        float* __restrict__ out, unsigned* __restrict__ bar) {
    __shared__ float red[2][8][3][4][64];   // 48 KB
    __shared__ unsigned ecnt;
    float* hall = out + NBATCH * HID;

    const int tid = threadIdx.x;
    const int l   = tid & 63;
    const int w   = tid >> 6;              // 0..7
    const int xcd = blockIdx.x & 7;
    const int j   = blockIdx.x >> 3;
    const int nb  = xcd + 8 * (j >> 2);
    const int mq  = j & 3;
    const int cb  = nb * 16;

    const int m    = mq * 16 + (l & 15);
    const int koff = (l >> 4) * 8;
    const int colz = cb + (l & 15);
    const int kbase = D_IN + 128 * w;

    unsigned* gcons = bar + mq * 1024 + w * 64;
    unsigned* gprod = bar + mq * 1024 + (nb >> 3) * 64;

    short8 Bh[3][4], Bl[3][4];
    #pragma unroll
    for (int g = 0; g < 3; ++g) {
        #pragma unroll
        for (int s = 0; s < 4; ++s) {
            const size_t o = (size_t)(colz + g * HID) * KTOT + kbase + 32 * s + koff;
            Bh[g][s] = *(const short8*)(WBh + o);
            Bl[g][s] = *(const short8*)(WBl + o);
        }
    }
    #pragma unroll
    for (int g = 0; g < 3; ++g) {
        #pragma unroll
        for (int s = 0; s < 4; ++s) {
            asm volatile("" : "+v"(Bh[g][s]));
            asm volatile("" : "+v"(Bl[g][s]));
        }
    }

    const int r2 = tid >> 6;
    const int l2 = tid & 63;
    const int be = mq * 16 + (l2 >> 4) * 4 + r2;   // C layout (m89)
    const int ce = cb + (l2 & 15);
    float hreg = 0.f;
    if (tid == 0) ecnt = 0u;

    for (int t = 0; t < SEQ; ++t) {
        f32x4 aZ = {0.f,0.f,0.f,0.f}, aR = {0.f,0.f,0.f,0.f}, aN = {0.f,0.f,0.f,0.f};
        if (t > 0) {
            const unsigned tgt = 8u * (unsigned)t;
            while (__hip_atomic_load(gcons, __ATOMIC_RELAXED,
                                     __HIP_MEMORY_SCOPE_AGENT) < tgt)
                __builtin_amdgcn_s_sleep(2);
            const float* hp = hall + ((size_t)m * SEQ + (t - 1)) * HID
                              + (kbase - D_IN) + koff;
            f32x4 h0, h1, h2, h3, h4, h5, h6, h7;
            asm volatile(
                "global_load_dwordx4 %0, %8, off sc0 sc1\n\t"
                "global_load_dwordx4 %1, %8, off offset:16 sc0 sc1\n\t"
                "global_load_dwordx4 %2, %8, off offset:128 sc0 sc1\n\t"
                "global_load_dwordx4 %3, %8, off offset:144 sc0 sc1\n\t"
                "global_load_dwordx4 %4, %8, off offset:256 sc0 sc1\n\t"
                "global_load_dwordx4 %5, %8, off offset:272 sc0 sc1\n\t"
                "global_load_dwordx4 %6, %8, off offset:384 sc0 sc1\n\t"
                "global_load_dwordx4 %7, %8, off offset:400 sc0 sc1\n\t"
                "s_waitcnt vmcnt(0)"
                : "=&v"(h0), "=&v"(h1), "=&v"(h2), "=&v"(h3),
                  "=&v"(h4), "=&v"(h5), "=&v"(h6), "=&v"(h7)
                : "v"(hp));
            #define SUBT(si, va, vb) { \
                short8 ahi, alo; cvt8((va), (vb), ahi, alo); \
                aZ = MFMA(ahi, Bh[0][si], aZ); aZ = MFMA(ahi, Bl[0][si], aZ); \
                aZ = MFMA(alo, Bh[0][si], aZ); \
                aR = MFMA(ahi, Bh[1][si], aR); aR = MFMA(ahi, Bl[1][si], aR); \
                aR = MFMA(alo, Bh[1][si], aR); \
                aN = MFMA(ahi, Bh[2][si], aN); aN = MFMA(ahi, Bl[2][si], aN); \
                aN = MFMA(alo, Bh[2][si], aN); }
            SUBT(0, h0, h1)
            SUBT(1, h2, h3)
            SUBT(2, h4, h5)
            SUBT(3, h6, h7)
            #undef SUBT
        }

        const int buf = t & 1;
        #pragma unroll
        for (int r = 0; r < 4; ++r) {
            red[buf][w][0][r][l] = aZ[r];
            red[buf][w][1][r][l] = aR[r];
            red[buf][w][2][r][l] = aN[r];
        }
        __syncthreads();   // red[t] published (single barrier per step)

        if (tid < 256) {
            const size_t xb = ((size_t)be * SEQ + t) * K3 + ce;
            float xpz = xp[xb];
            float xpr = xp[xb + HID];
            float xpn = xp[xb + 2 * HID];
            float sz = xpz, sr = xpr, snh = 0.f;
            #pragma unroll
            for (int wv = 0; wv < 8; ++wv) {
                sz  += red[buf][wv][0][r2][l2];
                sr  += red[buf][wv][1][r2][l2];
                snh += red[buf][wv][2][r2][l2];
            }
            float z   = 1.f / (1.f + __expf(-sz));
            float rr  = 1.f / (1.f + __expf(-sr));
            float pre = xpn + rr * snh;
            float e2  = __expf(2.f * pre);
            float n   = 1.f - 2.f / (e2 + 1.f);
            float h   = (1.f - z) * n + z * hreg;
            hreg = h;
            float* hw = hall + ((size_t)be * SEQ + t) * HID + ce;
            asm volatile("global_store_dword %0, %1, off sc0 sc1"
                         :: "v"(hw), "v"(h) : "memory");
            if (t == SEQ - 1) out[(size_t)be * HID + ce] = h;
            asm volatile("s_waitcnt vmcnt(0)" ::: "memory");
            if ((tid & 63) == 0) {
                unsigned eo = __hip_atomic_fetch_add(&ecnt, 1u, __ATOMIC_ACQ_REL,
                                                     __HIP_MEMORY_SCOPE_WORKGROUP);
                if (eo == 4u * (unsigned)(t + 1) - 1u)
                    __hip_atomic_fetch_add(gprod, 1u, __ATOMIC_RELEASE,
                                           __HIP_MEMORY_SCOPE_AGENT);
            }
        }
    }
}

// ---------------- fallback (round-9 path, verbatim) for small ws_size ----------------
__global__ __attribute__((amdgpu_waves_per_eu(3, 3)))
__launch_bounds__(768) void gru_persist_fb(
        const float* __restrict__ x, const float* __restrict__ bin,
        const __bf16* __restrict__ WBh, const __bf16* __restrict__ WBl,
        float* __restrict__ out, unsigned* __restrict__ bar) {
    __shared__ float red[12][3][4][64];
    __shared__ unsigned ecnt;
    float* hall = out + NBATCH * HID;
    const int tid = threadIdx.x;
    const int l   = tid & 63;
    const int w   = tid >> 6;
    const int xcd = blockIdx.x & 7;
    const int j   = blockIdx.x >> 3;
    const int nb  = xcd + 8 * (j >> 2);
    const int mq  = j & 3;
    const int cb  = nb * 16;
    const int m    = mq * 16 + (l & 15);
    const int koff = (l >> 4) * 8;
    const int colz = cb + (l & 15);
    const bool isH = (w < 8);
    const int kbase = isH ? (D_IN + 128 * w) : (128 * (w - 8));
    unsigned* gcons = bar + mq * 1024 + w * 64;
    unsigned* gprod = bar + mq * 1024 + (nb >> 3) * 64;
    short8 Bh[3][4], Bl[3][4];
    #pragma unroll
    for (int g = 0; g < 3; ++g)
        #pragma unroll
        for (int s = 0; s < 4; ++s) {
            const size_t o = (size_t)(colz + g * HID) * KTOT + kbase + 32 * s + koff;
            Bh[g][s] = *(const short8*)(WBh + o);
            Bl[g][s] = *(const short8*)(WBl + o);
        }
    #pragma unroll
    for (int g = 0; g < 3; ++g)
        #pragma unroll
        for (int s = 0; s < 4; ++s) {
            asm volatile("" : "+v"(Bh[g][s]));
            asm volatile("" : "+v"(Bl[g][s]));
        }
    const int r2 = tid >> 6;
    const int l2 = tid & 63;
    const int be = mq * 16 + (l2 >> 4) * 4 + r2;
    const int ce = cb + (l2 & 15);
    float bz = 0.f, br = 0.f, bnb = 0.f, hreg = 0.f;
    if (tid < 256) { bz = bin[ce]; br = bin[HID + ce]; bnb = bin[2 * HID + ce]; }
    if (tid == 0) ecnt = 0u;
    for (int t = 0; t < SEQ; ++t) {
        f32x4 aZ = {0.f,0.f,0.f,0.f}, aR = {0.f,0.f,0.f,0.f}, aN = {0.f,0.f,0.f,0.f};
        if (isH) {
            if (t > 0) {
                const unsigned tgt = 8u * (unsigned)t;
                while (__hip_atomic_load(gcons, __ATOMIC_RELAXED,
                                         __HIP_MEMORY_SCOPE_AGENT) < tgt)
                    __builtin_amdgcn_s_sleep(2);
                const float* hp = hall + ((size_t)m * SEQ + (t - 1)) * HID
                                  + (kbase - D_IN) + koff;
                f32x4 h0, h1, h2, h3, h4, h5, h6, h7;
                asm volatile(
                    "global_load_dwordx4 %0, %8, off sc0 sc1\n\t"
                    "global_load_dwordx4 %1, %8, off offset:16 sc0 sc1\n\t"
                    "global_load_dwordx4 %2, %8, off offset:128 sc0 sc1\n\t"
                    "global_load_dwordx4 %3, %8, off offset:144 sc0 sc1\n\t"
                    "global_load_dwordx4 %4, %8, off offset:256 sc0 sc1\n\t"
                    "global_load_dwordx4 %5, %8, off offset:272 sc0 sc1\n\t"
                    "global_load_dwordx4 %6, %8, off offset:384 sc0 sc1\n\t"
                    "global_load_dwordx4 %7, %8, off offset:400 sc0 sc1\n\t"
                    "s_waitcnt vmcnt(0)"
                    : "=&v"(h0), "=&v"(h1), "=&v"(h2), "=&v"(h3),
                      "=&v"(h4), "=&v"(h5), "=&v"(h6), "=&v"(h7)
                    : "v"(hp));
                #define SUBT(si, va, vb) { \
                    short8 ahi, alo; cvt8((va), (vb), ahi, alo); \
                    aZ = MFMA(ahi, Bh[0][si], aZ); aZ = MFMA(ahi, Bl[0][si], aZ); \
                    aZ = MFMA(alo, Bh[0][si], aZ); \
                    aR = MFMA(ahi, Bh[1][si], aR); aR = MFMA(ahi, Bl[1][si], aR); \
                    aR = MFMA(alo, Bh[1][si], aR); \
                    aN = MFMA(ahi, Bh[2][si], aN); aN = MFMA(ahi, Bl[2][si], aN); \
                    aN = MFMA(alo, Bh[2][si], aN); }
                SUBT(0, h0, h1)
                SUBT(1, h2, h3)
                SUBT(2, h4, h5)
                SUBT(3, h6, h7)
                #undef SUBT
            }
        } else {
            const float* xpp = x + ((size_t)m * SEQ + t) * D_IN + kbase + koff;
            #pragma unroll
            for (int s = 0; s < 4; ++s) {
                f32x4 v0 = *(const f32x4*)(xpp + 32 * s);
                f32x4 v1 = *(const f32x4*)(xpp + 32 * s + 4);
                short8 ahi, alo;
                cvt8(v0, v1, ahi, alo);
                aZ = MFMA(ahi, Bh[0][s], aZ); aZ = MFMA(ahi, Bl[0][s], aZ);
                aZ = MFMA(alo, Bh[0][s], aZ);
                aR = MFMA(ahi, Bh[1][s], aR); aR = MFMA(ahi, Bl[1][s], aR);
                aR = MFMA(alo, Bh[1][s], aR);
                aN = MFMA(ahi, Bh[2][s], aN); aN = MFMA(ahi, Bl[2][s], aN);
                aN = MFMA(alo, Bh[2][s], aN);
            }
        }
        #pragma unroll
        for (int r = 0; r < 4; ++r) {
            red[w][0][r][l] = aZ[r];
            red[w][1][r][l] = aR[r];
            red[w][2][r][l] = aN[r];
        }
        __syncthreads();
        if (tid < 256) {
            float sz = 0.f, sr = 0.f, snx = 0.f, snh = 0.f;
            #pragma unroll
            for (int wv = 0; wv < 8; ++wv) {
                sz += red[wv][0][r2][l2]; sr += red[wv][1][r2][l2];
                snh += red[wv][2][r2][l2];
            }
            #pragma unroll
            for (int wv = 8; wv < 12; ++wv) {
                sz += red[wv][0][r2][l2]; sr += red[wv][1][r2][l2];
                snx += red[wv][2][r2][l2];
            }
            float z   = 1.f / (1.f + __expf(-(sz + bz)));
            float rr  = 1.f / (1.f + __expf(-(sr + br)));
            float pre = snx + bnb + rr * snh;
            float e2  = __expf(2.f * pre);
            float n   = 1.f - 2.f / (e2 + 1.f);
            float h   = (1.f - z) * n + z * hreg;
            hreg = h;
            float* hw = hall + ((size_t)be * SEQ + t) * HID + ce;
            asm volatile("global_store_dword %0, %1, off sc0 sc1"
                         :: "v"(hw), "v"(h) : "memory");
            if (t == SEQ - 1) out[(size_t)be * HID + ce] = h;
            asm volatile("s_waitcnt vmcnt(0)" ::: "memory");
            if ((tid & 63) == 0) {
                unsigned eo = __hip_atomic_fetch_add(&ecnt, 1u, __ATOMIC_ACQ_REL,
                                                     __HIP_MEMORY_SCOPE_WORKGROUP);
                if (eo == 4u * (unsigned)(t + 1) - 1u)
                    __hip_atomic_fetch_add(gprod, 1u, __ATOMIC_RELEASE,
                                           __HIP_MEMORY_SCOPE_AGENT);
            }
        }
        __syncthreads();
    }
}

extern "C" void kernel_launch(void* const* d_in, const int* in_sizes, int n_in,
                              void* d_out, int out_size, void* d_ws, size_t ws_size,
                              hipStream_t stream) {
    const float* x   = (const float*)d_in[0];
    const float* Win = (const float*)d_in[1];
    const float* bin = (const float*)d_in[2];
    const float* Wh  = (const float*)d_in[3];
    float* out = (float*)d_out;

    __bf16* WBh = (__bf16*)d_ws;
    __bf16* WBl = (__bf16*)d_ws + (size_t)WB_ELEMS;
    const size_t bar_off = (size_t)2 * WB_ELEMS * sizeof(__bf16);   // 18.87 MB
    unsigned* bar = (unsigned*)((char*)d_ws + bar_off);
    const size_t xp_off = bar_off + (1u << 20);                      // +1 MB
    float* xp = (float*)((char*)d_ws + xp_off);

    hipMemsetAsync(bar, 0, 16384, stream);
    hipLaunchKernelGGL(build_wt, dim3((WB_ELEMS + 255) / 256), dim3(256), 0, stream,
                       Win, Wh, WBh, WBl);
    if (ws_size >= xp_off + XP_BYTES) {
        hipLaunchKernelGGL(xproj_all, dim3(XP_ROWS / 16, K3 / 48), dim3(256), 0,
                           stream, x, bin, WBh, WBl, xp);
        hipLaunchKernelGGL(gru_persist2, dim3(NBLK), dim3(512), 0, stream,
                           xp, WBh, WBl, out, bar);
    } else {
        hipLaunchKernelGGL(gru_persist_fb, dim3(NBLK), dim3(768), 0, stream,
                           x, bin, WBh, WBl, out, bar);
    }
}

// Round 11
// 4410.845 us; speedup vs baseline: 1.5306x; 1.5306x over previous
//
#include <hip/hip_runtime.h>
#include <math.h>

#define D_IN   512
#define HID    1024
#define SEQ    512
#define NBATCH 64
#define K3     3072
#define KTOT   1536
#define WB_ELEMS (K3 * KTOT)
#define NBLK   256
#define BLOCK_T 768   // 12 waves: 0-7 h-part (fp16, K=128 each), 8-11 x-part (bf16, K=128)

typedef __attribute__((ext_vector_type(8))) short short8;
typedef __attribute__((ext_vector_type(4))) float f32x4;
typedef _Float16 half8 __attribute__((ext_vector_type(8)));

#define MFMA_BF16(a, b, c) __builtin_amdgcn_mfma_f32_16x16x32_bf16((a), (b), (c), 0, 0, 0)
#define MFMA_F16(a, b, c)  __builtin_amdgcn_mfma_f32_16x16x32_f16((a), (b), (c), 0, 0, 0)

// ---------------- build fused transposed weight planes ----------------
// [col 0..3071][k 0..1535]; k<512 (x-part): bf16 hi/lo bits; k>=512 (h-part): fp16 hi/lo bits.
__global__ __launch_bounds__(256) void build_wt(const float* __restrict__ Win,
                                                const float* __restrict__ Wh,
                                                unsigned short* __restrict__ WBh,
                                                unsigned short* __restrict__ WBl) {
    int idx = blockIdx.x * 256 + threadIdx.x;
    if (idx >= WB_ELEMS) return;
    int k   = idx % KTOT;
    int col = idx / KTOT;
    float v = (k < D_IN) ? Win[(size_t)k * K3 + col]
                         : Wh[(size_t)(k - D_IN) * K3 + col];
    unsigned short hb, lb;
    if (k < D_IN) {
        __bf16 h = (__bf16)v;
        hb = __builtin_bit_cast(unsigned short, h);
        lb = __builtin_bit_cast(unsigned short, (__bf16)(v - (float)h));
    } else {
        _Float16 h = (_Float16)v;
        hb = __builtin_bit_cast(unsigned short, h);
        lb = __builtin_bit_cast(unsigned short, (_Float16)(v - (float)h));
    }
    WBh[idx] = hb;
    WBl[idx] = lb;
}

__device__ __forceinline__ void cvt8(const f32x4& v0, const f32x4& v1,
                                     short8& ahi, short8& alo) {
    float af[8] = {v0[0], v0[1], v0[2], v0[3], v1[0], v1[1], v1[2], v1[3]};
    #pragma unroll
    for (int j = 0; j < 8; ++j) {
        __bf16 hb = (__bf16)af[j];
        __bf16 lb = (__bf16)(af[j] - (float)hb);
        ahi[j] = __builtin_bit_cast(short, hb);
        alo[j] = __builtin_bit_cast(short, lb);
    }
}

// ---------------- persistent GRU: fp16 h-exchange ring ----------------
// Grid 256 x 768. Block (mq=j&3, nb=xcd+8*(j>>2)), xcd=bid&7.
// h state exchanged via hx[2][64][1024] fp16 ring (8 MB/step L3 traffic, was 16
// fp32). h-waves load 4x dwordx4 (=32 halfs) and feed f16 MFMA DIRECTLY (no cvt).
// fp32 h_all (harness output) written off-critical-path with normal cached
// stores (flushed at kernel end; nothing reads it in-kernel).
// Ring-2 WAR safety: producer writes slot t&1 at step t; all consumers read it
// during step t+1; producer reaches step t+2 only after gcons>=8(t+1), which
// requires every block's t+1 epilogue, which follows its slot reads.
// Sync: dataflow counters (round 9): ecnt(LDS) -> gprod RMW (8/line) ->
// consumer wave w polls gcons line w >= 8t.
__global__ __attribute__((amdgpu_waves_per_eu(3, 3)))
__launch_bounds__(BLOCK_T) void gru_persist(
        const float* __restrict__ x, const float* __restrict__ bin,
        const unsigned short* __restrict__ WBh, const unsigned short* __restrict__ WBl,
        float* __restrict__ out, unsigned* __restrict__ bar,
        unsigned short* __restrict__ hx) {
    __shared__ float red[2][12][3][4][64];   // 72 KB, double-buffered
    __shared__ unsigned ecnt;
    float* hall = out + NBATCH * HID;

    const int tid = threadIdx.x;
    const int l   = tid & 63;
    const int w   = tid >> 6;              // 0..11
    const int xcd = blockIdx.x & 7;
    const int j   = blockIdx.x >> 3;
    const int nb  = xcd + 8 * (j >> 2);
    const int mq  = j & 3;
    const int cb  = nb * 16;

    const int m    = mq * 16 + (l & 15);
    const int koff = (l >> 4) * 8;
    const int colz = cb + (l & 15);
    const bool isH = (w < 8);
    const int kbase = isH ? (D_IN + 128 * w) : (128 * (w - 8));

    unsigned* gcons = bar + mq * 1024 + w * 64;          // consumer poll (h-waves)
    unsigned* gprod = bar + mq * 1024 + (nb >> 3) * 64;  // producer bump

    // ---- one-time weight slice -> registers (h-part bits are fp16, x-part bf16)
    short8 Bh[3][4], Bl[3][4];
    #pragma unroll
    for (int g = 0; g < 3; ++g) {
        #pragma unroll
        for (int s = 0; s < 4; ++s) {
            const size_t o = (size_t)(colz + g * HID) * KTOT + kbase + 32 * s + koff;
            Bh[g][s] = *(const short8*)(WBh + o);
            Bl[g][s] = *(const short8*)(WBl + o);
        }
    }
    #pragma unroll
    for (int g = 0; g < 3; ++g) {
        #pragma unroll
        for (int s = 0; s < 4; ++s) {
            asm volatile("" : "+v"(Bh[g][s]));
            asm volatile("" : "+v"(Bl[g][s]));
        }
    }

    // epilogue constants (waves 0-3)
    const int r2 = tid >> 6;
    const int l2 = tid & 63;
    const int be = mq * 16 + (l2 >> 4) * 4 + r2;   // C layout (m89)
    const int ce = cb + (l2 & 15);
    float bz = 0.f, br = 0.f, bnb = 0.f, hreg = 0.f;
    if (tid < 256) {
        bz  = bin[ce];
        br  = bin[HID + ce];
        bnb = bin[2 * HID + ce];
    }
    asm volatile("" : "+v"(bz), "+v"(br), "+v"(bnb));
    if (tid == 0) ecnt = 0u;

    for (int t = 0; t < SEQ; ++t) {
        f32x4 aZ = {0.f,0.f,0.f,0.f}, aR = {0.f,0.f,0.f,0.f}, aN = {0.f,0.f,0.f,0.f};

        if (isH) {
            if (t > 0) {
                // dataflow wait: my 128-col hx slice fully stored for step t-1
                const unsigned tgt = 8u * (unsigned)t;
                while (__hip_atomic_load(gcons, __ATOMIC_RELAXED,
                                         __HIP_MEMORY_SCOPE_AGENT) < tgt)
                    __builtin_amdgcn_s_sleep(2);

                const unsigned short* hp = hx
                    + (size_t)((t - 1) & 1) * NBATCH * HID
                    + (size_t)m * HID + (kbase - D_IN) + koff;
                f32x4 q0, q1, q2, q3;
                asm volatile(
                    "global_load_dwordx4 %0, %4, off sc0 sc1\n\t"
                    "global_load_dwordx4 %1, %4, off offset:64 sc0 sc1\n\t"
                    "global_load_dwordx4 %2, %4, off offset:128 sc0 sc1\n\t"
                    "global_load_dwordx4 %3, %4, off offset:192 sc0 sc1\n\t"
                    "s_waitcnt vmcnt(0)"
                    : "=&v"(q0), "=&v"(q1), "=&v"(q2), "=&v"(q3)
                    : "v"(hp));
                #define SUBT16(si, q) { \
                    half8 ah = __builtin_bit_cast(half8, (q)); \
                    aZ = MFMA_F16(ah, __builtin_bit_cast(half8, Bh[0][si]), aZ); \
                    aZ = MFMA_F16(ah, __builtin_bit_cast(half8, Bl[0][si]), aZ); \
                    aR = MFMA_F16(ah, __builtin_bit_cast(half8, Bh[1][si]), aR); \
                    aR = MFMA_F16(ah, __builtin_bit_cast(half8, Bl[1][si]), aR); \
                    aN = MFMA_F16(ah, __builtin_bit_cast(half8, Bh[2][si]), aN); \
                    aN = MFMA_F16(ah, __builtin_bit_cast(half8, Bl[2][si]), aN); }
                SUBT16(0, q0)
                SUBT16(1, q1)
                SUBT16(2, q2)
                SUBT16(3, q3)
                #undef SUBT16
            }
        } else {
            const float* xp = x + ((size_t)m * SEQ + t) * D_IN + kbase + koff;
            #pragma unroll
            for (int s = 0; s < 4; ++s) {
                f32x4 v0 = *(const f32x4*)(xp + 32 * s);
                f32x4 v1 = *(const f32x4*)(xp + 32 * s + 4);
                short8 ahi, alo;
                cvt8(v0, v1, ahi, alo);
                aZ = MFMA_BF16(ahi, Bh[0][s], aZ); aZ = MFMA_BF16(ahi, Bl[0][s], aZ);
                aZ = MFMA_BF16(alo, Bh[0][s], aZ);
                aR = MFMA_BF16(ahi, Bh[1][s], aR); aR = MFMA_BF16(ahi, Bl[1][s], aR);
                aR = MFMA_BF16(alo, Bh[1][s], aR);
                aN = MFMA_BF16(ahi, Bh[2][s], aN); aN = MFMA_BF16(ahi, Bl[2][s], aN);
                aN = MFMA_BF16(alo, Bh[2][s], aN);
            }
        }

        const int buf = t & 1;
        #pragma unroll
        for (int r = 0; r < 4; ++r) {
            red[buf][w][0][r][l] = aZ[r];
            red[buf][w][1][r][l] = aR[r];
            red[buf][w][2][r][l] = aN[r];
        }
        __syncthreads();   // red[t] published (single barrier per step)

        if (tid < 256) {
            float sz = 0.f, sr = 0.f, snx = 0.f, snh = 0.f;
            #pragma unroll
            for (int wv = 0; wv < 8; ++wv) {
                sz  += red[buf][wv][0][r2][l2];
                sr  += red[buf][wv][1][r2][l2];
                snh += red[buf][wv][2][r2][l2];
            }
            #pragma unroll
            for (int wv = 8; wv < 12; ++wv) {
                sz  += red[buf][wv][0][r2][l2];
                sr  += red[buf][wv][1][r2][l2];
                snx += red[buf][wv][2][r2][l2];
            }
            float z   = 1.f / (1.f + __expf(-(sz + bz)));
            float rr  = 1.f / (1.f + __expf(-(sr + br)));
            float pre = snx + bnb + rr * snh;
            float e2  = __expf(2.f * pre);
            float n   = 1.f - 2.f / (e2 + 1.f);
            float h   = (1.f - z) * n + z * hreg;
            hreg = h;

            // critical-path exchange store: fp16 write-through, then drain
            unsigned hv = (unsigned)__builtin_bit_cast(unsigned short, (_Float16)h);
            unsigned short* hxp = hx + (size_t)(t & 1) * NBATCH * HID
                                     + (size_t)be * HID + ce;
            asm volatile("global_store_short %0, %1, off sc0 sc1"
                         :: "v"(hxp), "v"(hv) : "memory");
            asm volatile("s_waitcnt vmcnt(0)" ::: "memory");
            if ((tid & 63) == 0) {
                unsigned eo = __hip_atomic_fetch_add(&ecnt, 1u, __ATOMIC_ACQ_REL,
                                                     __HIP_MEMORY_SCOPE_WORKGROUP);
                if (eo == 4u * (unsigned)(t + 1) - 1u)
                    __hip_atomic_fetch_add(gprod, 1u, __ATOMIC_RELEASE,
                                           __HIP_MEMORY_SCOPE_AGENT);
            }
            // archival fp32 writes: off critical path, normal cached stores
            hall[((size_t)be * SEQ + t) * HID + ce] = h;
            if (t == SEQ - 1) out[(size_t)be * HID + ce] = h;
        }
    }
}

extern "C" void kernel_launch(void* const* d_in, const int* in_sizes, int n_in,
                              void* d_out, int out_size, void* d_ws, size_t ws_size,
                              hipStream_t stream) {
    const float* x   = (const float*)d_in[0];
    const float* Win = (const float*)d_in[1];
    const float* bin = (const float*)d_in[2];
    const float* Wh  = (const float*)d_in[3];
    float* out = (float*)d_out;

    unsigned short* WBh = (unsigned short*)d_ws;                       // 9.44 MB
    unsigned short* WBl = (unsigned short*)d_ws + (size_t)WB_ELEMS;    // 9.44 MB
    const size_t bar_off = (size_t)2 * WB_ELEMS * sizeof(unsigned short);
    unsigned* bar = (unsigned*)((char*)d_ws + bar_off);                // 16 KB used
    const size_t hx_off = bar_off + (1u << 20);
    unsigned short* hx = (unsigned short*)((char*)d_ws + hx_off);      // 256 KB

    hipMemsetAsync(bar, 0, 16384, stream);   // replay-safe counter reset
    hipLaunchKernelGGL(build_wt, dim3((WB_ELEMS + 255) / 256), dim3(256), 0, stream,
                       Win, Wh, WBh, WBl);
    hipLaunchKernelGGL(gru_persist, dim3(NBLK), dim3(BLOCK_T), 0, stream,
                       x, bin, WBh, WBl, out, bar, hx);
}

// Round 12
// 3356.677 us; speedup vs baseline: 2.0113x; 1.3141x over previous
//
#include <hip/hip_runtime.h>
#include <math.h>

#define D_IN   512
#define HID    1024
#define SEQ    512
#define NBATCH 64
#define K3     3072
#define KTOT   1536
#define WB_ELEMS (K3 * KTOT)
#define NBLK   256
#define BLOCK_T 768   // 12 waves: 0-7 h-part (fp16, K=128 each), 8-11 x-part (bf16, K=128)

typedef __attribute__((ext_vector_type(8))) short short8;
typedef __attribute__((ext_vector_type(4))) float f32x4;
typedef __attribute__((ext_vector_type(4))) unsigned u32x4;
typedef _Float16 half8 __attribute__((ext_vector_type(8)));

#define MFMA_BF16(a, b, c) __builtin_amdgcn_mfma_f32_16x16x32_bf16((a), (b), (c), 0, 0, 0)
#define MFMA_F16(a, b, c)  __builtin_amdgcn_mfma_f32_16x16x32_f16((a), (b), (c), 0, 0, 0)

// ---------------- build fused transposed weight planes ----------------
// [col 0..3071][k 0..1535]; k<512 (x-part): bf16 hi/lo bits; k>=512 (h-part): fp16 hi/lo bits.
__global__ __launch_bounds__(256) void build_wt(const float* __restrict__ Win,
                                                const float* __restrict__ Wh,
                                                unsigned short* __restrict__ WBh,
                                                unsigned short* __restrict__ WBl) {
    int idx = blockIdx.x * 256 + threadIdx.x;
    if (idx >= WB_ELEMS) return;
    int k   = idx % KTOT;
    int col = idx / KTOT;
    float v = (k < D_IN) ? Win[(size_t)k * K3 + col]
                         : Wh[(size_t)(k - D_IN) * K3 + col];
    unsigned short hb, lb;
    if (k < D_IN) {
        __bf16 h = (__bf16)v;
        hb = __builtin_bit_cast(unsigned short, h);
        lb = __builtin_bit_cast(unsigned short, (__bf16)(v - (float)h));
    } else {
        _Float16 h = (_Float16)v;
        hb = __builtin_bit_cast(unsigned short, h);
        lb = __builtin_bit_cast(unsigned short, (_Float16)(v - (float)h));
    }
    WBh[idx] = hb;
    WBl[idx] = lb;
}

__device__ __forceinline__ void cvt8(const f32x4& v0, const f32x4& v1,
                                     short8& ahi, short8& alo) {
    float af[8] = {v0[0], v0[1], v0[2], v0[3], v1[0], v1[1], v1[2], v1[3]};
    #pragma unroll
    for (int j = 0; j < 8; ++j) {
        __bf16 hb = (__bf16)af[j];
        __bf16 lb = (__bf16)(af[j] - (float)hb);
        ahi[j] = __builtin_bit_cast(short, hb);
        alo[j] = __builtin_bit_cast(short, lb);
    }
}

// ---------------- persistent GRU: tag-in-data h exchange ----------------
// Grid 256 x 768. Block (mq=j&3, nb=xcd+8*(j>>2)), xcd=bid&7.
// Exchange word hx2[slot][b][c] = (tag<<16) | fp16(h), tag = t+1 at step t,
// slot = t&1. Producers: ONE fire-and-forget sc0sc1 dword store per (b,c) —
// no drain, no counters, no RMW. Consumers: poll own 32 words (8x dwordx4
// sc1) until all tags == t, then unpack via v_perm and feed f16 MFMA.
// Ring-2 WAR proof: P overwrites slot t&1 (tag t+3) in its step-t+2 epilogue,
// which follows P's step-t+2 polls of ALL blocks' tag-t+2 data; each block C
// wrote tag t+2 only after its step-t+1 loads of slot-t&1 data returned. So
// every overwrite happens-after every read of the overwritten data.
// Tags 1..512 distinct (no wrap); ring memset 0 per launch (replay-safe).
__global__ __attribute__((amdgpu_waves_per_eu(3, 3)))
__launch_bounds__(BLOCK_T) void gru_persist(
        const float* __restrict__ x, const float* __restrict__ bin,
        const unsigned short* __restrict__ WBh, const unsigned short* __restrict__ WBl,
        float* __restrict__ out, unsigned* __restrict__ hx2) {
    __shared__ float red[2][12][3][4][64];   // 72 KB, double-buffered
    float* hall = out + NBATCH * HID;

    const int tid = threadIdx.x;
    const int l   = tid & 63;
    const int w   = tid >> 6;              // 0..11
    const int xcd = blockIdx.x & 7;
    const int j   = blockIdx.x >> 3;
    const int nb  = xcd + 8 * (j >> 2);
    const int mq  = j & 3;
    const int cb  = nb * 16;

    const int m    = mq * 16 + (l & 15);
    const int koff = (l >> 4) * 8;
    const int colz = cb + (l & 15);
    const bool isH = (w < 8);
    const int kbase = isH ? (D_IN + 128 * w) : (128 * (w - 8));

    // ---- one-time weight slice -> registers (h-part fp16 bits, x-part bf16 bits)
    short8 Bh[3][4], Bl[3][4];
    #pragma unroll
    for (int g = 0; g < 3; ++g) {
        #pragma unroll
        for (int s = 0; s < 4; ++s) {
            const size_t o = (size_t)(colz + g * HID) * KTOT + kbase + 32 * s + koff;
            Bh[g][s] = *(const short8*)(WBh + o);
            Bl[g][s] = *(const short8*)(WBl + o);
        }
    }
    #pragma unroll
    for (int g = 0; g < 3; ++g) {
        #pragma unroll
        for (int s = 0; s < 4; ++s) {
            asm volatile("" : "+v"(Bh[g][s]));
            asm volatile("" : "+v"(Bl[g][s]));
        }
    }

    // epilogue constants (waves 0-3)
    const int r2 = tid >> 6;
    const int l2 = tid & 63;
    const int be = mq * 16 + (l2 >> 4) * 4 + r2;   // C layout (m89)
    const int ce = cb + (l2 & 15);
    float bz = 0.f, br = 0.f, bnb = 0.f, hreg = 0.f;
    if (tid < 256) {
        bz  = bin[ce];
        br  = bin[HID + ce];
        bnb = bin[2 * HID + ce];
    }
    asm volatile("" : "+v"(bz), "+v"(br), "+v"(bnb));

    for (int t = 0; t < SEQ; ++t) {
        f32x4 aZ = {0.f,0.f,0.f,0.f}, aR = {0.f,0.f,0.f,0.f}, aN = {0.f,0.f,0.f,0.f};

        if (isH) {
            if (t > 0) {
                // poll own data words until every tag == t (data of step t-1)
                const unsigned* hp = hx2 + (size_t)((t - 1) & 1) * NBATCH * HID
                                         + (size_t)m * HID + (kbase - D_IN) + koff;
                const unsigned tagexp = (unsigned)t;
                u32x4 q0, q1, q2, q3, q4, q5, q6, q7;
                while (true) {
                    asm volatile(
                        "global_load_dwordx4 %0, %8, off sc0 sc1\n\t"
                        "global_load_dwordx4 %1, %8, off offset:16 sc0 sc1\n\t"
                        "global_load_dwordx4 %2, %8, off offset:128 sc0 sc1\n\t"
                        "global_load_dwordx4 %3, %8, off offset:144 sc0 sc1\n\t"
                        "global_load_dwordx4 %4, %8, off offset:256 sc0 sc1\n\t"
                        "global_load_dwordx4 %5, %8, off offset:272 sc0 sc1\n\t"
                        "global_load_dwordx4 %6, %8, off offset:384 sc0 sc1\n\t"
                        "global_load_dwordx4 %7, %8, off offset:400 sc0 sc1\n\t"
                        "s_waitcnt vmcnt(0)"
                        : "=&v"(q0), "=&v"(q1), "=&v"(q2), "=&v"(q3),
                          "=&v"(q4), "=&v"(q5), "=&v"(q6), "=&v"(q7)
                        : "v"(hp));
                    unsigned acc;
                    #define CK4(q) (((q[0] >> 16) ^ tagexp) | ((q[1] >> 16) ^ tagexp) | \
                                    ((q[2] >> 16) ^ tagexp) | ((q[3] >> 16) ^ tagexp))
                    acc = CK4(q0) | CK4(q1) | CK4(q2) | CK4(q3)
                        | CK4(q4) | CK4(q5) | CK4(q6) | CK4(q7);
                    #undef CK4
                    if (!__any(acc != 0)) break;
                    __builtin_amdgcn_s_sleep(1);
                }
                // unpack fp16 payloads -> half8 per K-subtile, MFMA directly
                #define SUBT16(si, qa, qb) { \
                    unsigned u0 = __builtin_amdgcn_perm(qa[1], qa[0], 0x05040100); \
                    unsigned u1 = __builtin_amdgcn_perm(qa[3], qa[2], 0x05040100); \
                    unsigned u2 = __builtin_amdgcn_perm(qb[1], qb[0], 0x05040100); \
                    unsigned u3 = __builtin_amdgcn_perm(qb[3], qb[2], 0x05040100); \
                    u32x4 uu = {u0, u1, u2, u3}; \
                    half8 ah = __builtin_bit_cast(half8, uu); \
                    aZ = MFMA_F16(ah, __builtin_bit_cast(half8, Bh[0][si]), aZ); \
                    aZ = MFMA_F16(ah, __builtin_bit_cast(half8, Bl[0][si]), aZ); \
                    aR = MFMA_F16(ah, __builtin_bit_cast(half8, Bh[1][si]), aR); \
                    aR = MFMA_F16(ah, __builtin_bit_cast(half8, Bl[1][si]), aR); \
                    aN = MFMA_F16(ah, __builtin_bit_cast(half8, Bh[2][si]), aN); \
                    aN = MFMA_F16(ah, __builtin_bit_cast(half8, Bl[2][si]), aN); }
                SUBT16(0, q0, q1)
                SUBT16(1, q2, q3)
                SUBT16(2, q4, q5)
                SUBT16(3, q6, q7)
                #undef SUBT16
            }
        } else {
            const float* xp = x + ((size_t)m * SEQ + t) * D_IN + kbase + koff;
            #pragma unroll
            for (int s = 0; s < 4; ++s) {
                f32x4 v0 = *(const f32x4*)(xp + 32 * s);
                f32x4 v1 = *(const f32x4*)(xp + 32 * s + 4);
                short8 ahi, alo;
                cvt8(v0, v1, ahi, alo);
                aZ = MFMA_BF16(ahi, Bh[0][s], aZ); aZ = MFMA_BF16(ahi, Bl[0][s], aZ);
                aZ = MFMA_BF16(alo, Bh[0][s], aZ);
                aR = MFMA_BF16(ahi, Bh[1][s], aR); aR = MFMA_BF16(ahi, Bl[1][s], aR);
                aR = MFMA_BF16(alo, Bh[1][s], aR);
                aN = MFMA_BF16(ahi, Bh[2][s], aN); aN = MFMA_BF16(ahi, Bl[2][s], aN);
                aN = MFMA_BF16(alo, Bh[2][s], aN);
            }
        }

        const int buf = t & 1;
        #pragma unroll
        for (int r = 0; r < 4; ++r) {
            red[buf][w][0][r][l] = aZ[r];
            red[buf][w][1][r][l] = aR[r];
            red[buf][w][2][r][l] = aN[r];
        }
        __syncthreads();   // red[t] published (single barrier per step)

        if (tid < 256) {
            float sz = 0.f, sr = 0.f, snx = 0.f, snh = 0.f;
            #pragma unroll
            for (int wv = 0; wv < 8; ++wv) {
                sz  += red[buf][wv][0][r2][l2];
                sr  += red[buf][wv][1][r2][l2];
                snh += red[buf][wv][2][r2][l2];
            }
            #pragma unroll
            for (int wv = 8; wv < 12; ++wv) {
                sz  += red[buf][wv][0][r2][l2];
                sr  += red[buf][wv][1][r2][l2];
                snx += red[buf][wv][2][r2][l2];
            }
            float z   = 1.f / (1.f + __expf(-(sz + bz)));
            float rr  = 1.f / (1.f + __expf(-(sr + br)));
            float pre = snx + bnb + rr * snh;
            float e2  = __expf(2.f * pre);
            float n   = 1.f - 2.f / (e2 + 1.f);
            float h   = (1.f - z) * n + z * hreg;
            hreg = h;

            // tag-in-data exchange store: fire-and-forget (no drain, no flag)
            unsigned hv = (unsigned)__builtin_bit_cast(unsigned short, (_Float16)h)
                        | ((unsigned)(t + 1) << 16);
            unsigned* hxp = hx2 + (size_t)(t & 1) * NBATCH * HID
                                + (size_t)be * HID + ce;
            asm volatile("global_store_dword %0, %1, off sc0 sc1"
                         :: "v"(hxp), "v"(hv) : "memory");
            // archival fp32 writes: off critical path, normal cached stores
            hall[((size_t)be * SEQ + t) * HID + ce] = h;
            if (t == SEQ - 1) out[(size_t)be * HID + ce] = h;
        }
    }
}

extern "C" void kernel_launch(void* const* d_in, const int* in_sizes, int n_in,
                              void* d_out, int out_size, void* d_ws, size_t ws_size,
                              hipStream_t stream) {
    const float* x   = (const float*)d_in[0];
    const float* Win = (const float*)d_in[1];
    const float* bin = (const float*)d_in[2];
    const float* Wh  = (const float*)d_in[3];
    float* out = (float*)d_out;

    unsigned short* WBh = (unsigned short*)d_ws;                       // 9.44 MB
    unsigned short* WBl = (unsigned short*)d_ws + (size_t)WB_ELEMS;    // 9.44 MB
    const size_t hx_off = ((size_t)2 * WB_ELEMS * sizeof(unsigned short) + (1u << 20))
                          & ~((size_t)(1u << 20) - 1);                 // 1MB-aligned
    unsigned* hx2 = (unsigned*)((char*)d_ws + hx_off);                 // 512 KB

    hipMemsetAsync(hx2, 0, (size_t)2 * NBATCH * HID * 4, stream);  // tags=0, replay-safe
    hipLaunchKernelGGL(build_wt, dim3((WB_ELEMS + 255) / 256), dim3(256), 0, stream,
                       Win, Wh, WBh, WBl);
    hipLaunchKernelGGL(gru_persist, dim3(NBLK), dim3(BLOCK_T), 0, stream,
                       x, bin, WBh, WBl, out, hx2);
}

// Round 13
// 2556.471 us; speedup vs baseline: 2.6409x; 1.3130x over previous
//
#include <hip/hip_runtime.h>
#include <math.h>

#define D_IN   512
#define HID    1024
#define SEQ    512
#define NBATCH 64
#define K3     3072
#define KTOT   1536
#define WB_ELEMS (K3 * KTOT)
#define NBLK   256
#define BLOCK_T 768   // 12 waves: 0-7 h-part (fp16, K=128 each), 8-11 x-part (bf16, K=128)

typedef __attribute__((ext_vector_type(8))) short short8;
typedef __attribute__((ext_vector_type(4))) float f32x4;
typedef __attribute__((ext_vector_type(4))) unsigned u32x4;
typedef _Float16 half8 __attribute__((ext_vector_type(8)));

#define MFMA_BF16(a, b, c) __builtin_amdgcn_mfma_f32_16x16x32_bf16((a), (b), (c), 0, 0, 0)
#define MFMA_F16(a, b, c)  __builtin_amdgcn_mfma_f32_16x16x32_f16((a), (b), (c), 0, 0, 0)

// ---------------- build fused transposed weight planes ----------------
// [col 0..3071][k 0..1535]; k<512 (x-part): bf16 hi/lo bits; k>=512 (h-part): fp16 hi/lo bits.
__global__ __launch_bounds__(256) void build_wt(const float* __restrict__ Win,
                                                const float* __restrict__ Wh,
                                                unsigned short* __restrict__ WBh,
                                                unsigned short* __restrict__ WBl) {
    int idx = blockIdx.x * 256 + threadIdx.x;
    if (idx >= WB_ELEMS) return;
    int k   = idx % KTOT;
    int col = idx / KTOT;
    float v = (k < D_IN) ? Win[(size_t)k * K3 + col]
                         : Wh[(size_t)(k - D_IN) * K3 + col];
    unsigned short hb, lb;
    if (k < D_IN) {
        __bf16 h = (__bf16)v;
        hb = __builtin_bit_cast(unsigned short, h);
        lb = __builtin_bit_cast(unsigned short, (__bf16)(v - (float)h));
    } else {
        _Float16 h = (_Float16)v;
        hb = __builtin_bit_cast(unsigned short, h);
        lb = __builtin_bit_cast(unsigned short, (_Float16)(v - (float)h));
    }
    WBh[idx] = hb;
    WBl[idx] = lb;
}

__device__ __forceinline__ void cvt8(const f32x4& v0, const f32x4& v1,
                                     short8& ahi, short8& alo) {
    float af[8] = {v0[0], v0[1], v0[2], v0[3], v1[0], v1[1], v1[2], v1[3]};
    #pragma unroll
    for (int j = 0; j < 8; ++j) {
        __bf16 hb = (__bf16)af[j];
        __bf16 lb = (__bf16)(af[j] - (float)hb);
        ahi[j] = __builtin_bit_cast(short, hb);
        alo[j] = __builtin_bit_cast(short, lb);
    }
}

// ---------------- persistent GRU: tag-in-data + cheap flag poll ----------------
// Exchange word hx2[slot][b][c] = (tag<<16)|fp16(h), tag = t+1 at step t, slot = t&1.
// NEW vs round 12: detection decoupled from transfer. Producer epilogue wave wv
// fire-and-forgets flags[mq][nb][wv] = t+1 AFTER its 64 data stores (same-wave
// program order; no drain). Consumer wave polls 32 flag dwords (128 B/iter,
// ~60x less L3 traffic than re-loading the 8KB slice) with MONOTONIC >= t
// check, then loads the data burst ONCE and verifies embedded tags == t
// (flag/data arrival order is not guaranteed; retry is rare).
// Flag >= t is immune to fast-producer overwrite (flags only grow within a
// launch); 0xAA poison or stale values fail into the tag-verify loop, which is
// exact. Ring-2 WAR proof unchanged from round 12: P overwrites slot (t-1)&1
// only at step t+1, gated on observing tags==t+1 from every block, which
// happens-after every block's step-t reads of that slot returned.
__global__ __attribute__((amdgpu_waves_per_eu(3, 3)))
__launch_bounds__(BLOCK_T) void gru_persist(
        const float* __restrict__ x, const float* __restrict__ bin,
        const unsigned short* __restrict__ WBh, const unsigned short* __restrict__ WBl,
        float* __restrict__ out, unsigned* __restrict__ hx2,
        unsigned* __restrict__ flags) {
    __shared__ float red[2][12][3][4][64];   // 72 KB, double-buffered
    float* hall = out + NBATCH * HID;

    const int tid = threadIdx.x;
    const int l   = tid & 63;
    const int w   = tid >> 6;              // 0..11
    const int xcd = blockIdx.x & 7;
    const int j   = blockIdx.x >> 3;
    const int nb  = xcd + 8 * (j >> 2);
    const int mq  = j & 3;
    const int cb  = nb * 16;

    const int m    = mq * 16 + (l & 15);
    const int koff = (l >> 4) * 8;
    const int colz = cb + (l & 15);
    const bool isH = (w < 8);
    const int kbase = isH ? (D_IN + 128 * w) : (128 * (w - 8));

    // consumer flag addr: producer block (8w + (l&31)>>2) of my domain, wave (l&3)
    const unsigned* fp = flags + mq * 1024
                       + (8 * w + ((l & 31) >> 2)) * 16 + (l & 3);
    // producer flag addr (epilogue wave r2 of this block)
    unsigned* fprod = flags + mq * 1024 + nb * 16 + (tid >> 6);

    // ---- one-time weight slice -> registers (h-part fp16 bits, x-part bf16 bits)
    short8 Bh[3][4], Bl[3][4];
    #pragma unroll
    for (int g = 0; g < 3; ++g) {
        #pragma unroll
        for (int s = 0; s < 4; ++s) {
            const size_t o = (size_t)(colz + g * HID) * KTOT + kbase + 32 * s + koff;
            Bh[g][s] = *(const short8*)(WBh + o);
            Bl[g][s] = *(const short8*)(WBl + o);
        }
    }
    #pragma unroll
    for (int g = 0; g < 3; ++g) {
        #pragma unroll
        for (int s = 0; s < 4; ++s) {
            asm volatile("" : "+v"(Bh[g][s]));
            asm volatile("" : "+v"(Bl[g][s]));
        }
    }

    // epilogue constants (waves 0-3)
    const int r2 = tid >> 6;
    const int l2 = tid & 63;
    const int be = mq * 16 + (l2 >> 4) * 4 + r2;   // C layout (m89)
    const int ce = cb + (l2 & 15);
    float bz = 0.f, br = 0.f, bnb = 0.f, hreg = 0.f;
    if (tid < 256) {
        bz  = bin[ce];
        br  = bin[HID + ce];
        bnb = bin[2 * HID + ce];
    }
    asm volatile("" : "+v"(bz), "+v"(br), "+v"(bnb));

    for (int t = 0; t < SEQ; ++t) {
        f32x4 aZ = {0.f,0.f,0.f,0.f}, aR = {0.f,0.f,0.f,0.f}, aN = {0.f,0.f,0.f,0.f};

        if (isH) {
            if (t > 0) {
                const unsigned tagexp = (unsigned)t;
                // ---- cheap flag poll (128 B/wave/iter)
                while (true) {
                    unsigned f;
                    asm volatile("global_load_dword %0, %1, off sc0 sc1\n\t"
                                 "s_waitcnt vmcnt(0)"
                                 : "=v"(f) : "v"(fp));
                    if (__all(f >= tagexp)) break;
                    __builtin_amdgcn_s_sleep(1);
                }
                // ---- data burst, verify embedded tags (rare retry)
                const unsigned* hp = hx2 + (size_t)((t - 1) & 1) * NBATCH * HID
                                         + (size_t)m * HID + (kbase - D_IN) + koff;
                u32x4 q0, q1, q2, q3, q4, q5, q6, q7;
                while (true) {
                    asm volatile(
                        "global_load_dwordx4 %0, %8, off sc0 sc1\n\t"
                        "global_load_dwordx4 %1, %8, off offset:16 sc0 sc1\n\t"
                        "global_load_dwordx4 %2, %8, off offset:128 sc0 sc1\n\t"
                        "global_load_dwordx4 %3, %8, off offset:144 sc0 sc1\n\t"
                        "global_load_dwordx4 %4, %8, off offset:256 sc0 sc1\n\t"
                        "global_load_dwordx4 %5, %8, off offset:272 sc0 sc1\n\t"
                        "global_load_dwordx4 %6, %8, off offset:384 sc0 sc1\n\t"
                        "global_load_dwordx4 %7, %8, off offset:400 sc0 sc1\n\t"
                        "s_waitcnt vmcnt(0)"
                        : "=&v"(q0), "=&v"(q1), "=&v"(q2), "=&v"(q3),
                          "=&v"(q4), "=&v"(q5), "=&v"(q6), "=&v"(q7)
                        : "v"(hp));
                    unsigned acc;
                    #define CK4(q) (((q[0] >> 16) ^ tagexp) | ((q[1] >> 16) ^ tagexp) | \
                                    ((q[2] >> 16) ^ tagexp) | ((q[3] >> 16) ^ tagexp))
                    acc = CK4(q0) | CK4(q1) | CK4(q2) | CK4(q3)
                        | CK4(q4) | CK4(q5) | CK4(q6) | CK4(q7);
                    #undef CK4
                    if (!__any(acc != 0)) break;
                    __builtin_amdgcn_s_sleep(1);
                }
                // unpack fp16 payloads -> half8 per K-subtile, MFMA directly
                #define SUBT16(si, qa, qb) { \
                    unsigned u0 = __builtin_amdgcn_perm(qa[1], qa[0], 0x05040100); \
                    unsigned u1 = __builtin_amdgcn_perm(qa[3], qa[2], 0x05040100); \
                    unsigned u2 = __builtin_amdgcn_perm(qb[1], qb[0], 0x05040100); \
                    unsigned u3 = __builtin_amdgcn_perm(qb[3], qb[2], 0x05040100); \
                    u32x4 uu = {u0, u1, u2, u3}; \
                    half8 ah = __builtin_bit_cast(half8, uu); \
                    aZ = MFMA_F16(ah, __builtin_bit_cast(half8, Bh[0][si]), aZ); \
                    aZ = MFMA_F16(ah, __builtin_bit_cast(half8, Bl[0][si]), aZ); \
                    aR = MFMA_F16(ah, __builtin_bit_cast(half8, Bh[1][si]), aR); \
                    aR = MFMA_F16(ah, __builtin_bit_cast(half8, Bl[1][si]), aR); \
                    aN = MFMA_F16(ah, __builtin_bit_cast(half8, Bh[2][si]), aN); \
                    aN = MFMA_F16(ah, __builtin_bit_cast(half8, Bl[2][si]), aN); }
                SUBT16(0, q0, q1)
                SUBT16(1, q2, q3)
                SUBT16(2, q4, q5)
                SUBT16(3, q6, q7)
                #undef SUBT16
            }
        } else {
            const float* xp = x + ((size_t)m * SEQ + t) * D_IN + kbase + koff;
            #pragma unroll
            for (int s = 0; s < 4; ++s) {
                f32x4 v0 = *(const f32x4*)(xp + 32 * s);
                f32x4 v1 = *(const f32x4*)(xp + 32 * s + 4);
                short8 ahi, alo;
                cvt8(v0, v1, ahi, alo);
                aZ = MFMA_BF16(ahi, Bh[0][s], aZ); aZ = MFMA_BF16(ahi, Bl[0][s], aZ);
                aZ = MFMA_BF16(alo, Bh[0][s], aZ);
                aR = MFMA_BF16(ahi, Bh[1][s], aR); aR = MFMA_BF16(ahi, Bl[1][s], aR);
                aR = MFMA_BF16(alo, Bh[1][s], aR);
                aN = MFMA_BF16(ahi, Bh[2][s], aN); aN = MFMA_BF16(ahi, Bl[2][s], aN);
                aN = MFMA_BF16(alo, Bh[2][s], aN);
            }
        }

        const int buf = t & 1;
        #pragma unroll
        for (int r = 0; r < 4; ++r) {
            red[buf][w][0][r][l] = aZ[r];
            red[buf][w][1][r][l] = aR[r];
            red[buf][w][2][r][l] = aN[r];
        }
        __syncthreads();   // red[t] published (single barrier per step)

        if (tid < 256) {
            float sz = 0.f, sr = 0.f, snx = 0.f, snh = 0.f;
            #pragma unroll
            for (int wv = 0; wv < 8; ++wv) {
                sz  += red[buf][wv][0][r2][l2];
                sr  += red[buf][wv][1][r2][l2];
                snh += red[buf][wv][2][r2][l2];
            }
            #pragma unroll
            for (int wv = 8; wv < 12; ++wv) {
                sz  += red[buf][wv][0][r2][l2];
                sr  += red[buf][wv][1][r2][l2];
                snx += red[buf][wv][2][r2][l2];
            }
            float z   = 1.f / (1.f + __expf(-(sz + bz)));
            float rr  = 1.f / (1.f + __expf(-(sr + br)));
            float pre = snx + bnb + rr * snh;
            float e2  = __expf(2.f * pre);
            float n   = 1.f - 2.f / (e2 + 1.f);
            float h   = (1.f - z) * n + z * hreg;
            hreg = h;

            // data store (fire-and-forget), then this wave's flag (same wave ->
            // flag issues after all 64 data stores of this wave; verify covers
            // any L3 arrival reordering)
            unsigned hv = (unsigned)__builtin_bit_cast(unsigned short, (_Float16)h)
                        | ((unsigned)(t + 1) << 16);
            unsigned* hxp = hx2 + (size_t)(t & 1) * NBATCH * HID
                                + (size_t)be * HID + ce;
            asm volatile("global_store_dword %0, %1, off sc0 sc1"
                         :: "v"(hxp), "v"(hv) : "memory");
            if ((tid & 63) == 0) {
                unsigned fv = (unsigned)(t + 1);
                asm volatile("global_store_dword %0, %1, off sc0 sc1"
                             :: "v"(fprod), "v"(fv) : "memory");
            }
            // archival fp32 writes: off critical path, normal cached stores
            hall[((size_t)be * SEQ + t) * HID + ce] = h;
            if (t == SEQ - 1) out[(size_t)be * HID + ce] = h;
        }
    }
}

extern "C" void kernel_launch(void* const* d_in, const int* in_sizes, int n_in,
                              void* d_out, int out_size, void* d_ws, size_t ws_size,
                              hipStream_t stream) {
    const float* x   = (const float*)d_in[0];
    const float* Win = (const float*)d_in[1];
    const float* bin = (const float*)d_in[2];
    const float* Wh  = (const float*)d_in[3];
    float* out = (float*)d_out;

    unsigned short* WBh = (unsigned short*)d_ws;                       // 9.44 MB
    unsigned short* WBl = (unsigned short*)d_ws + (size_t)WB_ELEMS;    // 9.44 MB
    const size_t hx_off = ((size_t)2 * WB_ELEMS * sizeof(unsigned short) + (1u << 20))
                          & ~((size_t)(1u << 20) - 1);                 // 1MB-aligned
    unsigned* hx2   = (unsigned*)((char*)d_ws + hx_off);               // 512 KB
    unsigned* flags = hx2 + (size_t)2 * NBATCH * HID;                  // 16 KB

    // zero hx2 tags + flags every launch (replay-safe; graph-capturable)
    hipMemsetAsync(hx2, 0, (size_t)2 * NBATCH * HID * 4 + 4 * 1024 * 4, stream);
    hipLaunchKernelGGL(build_wt, dim3((WB_ELEMS + 255) / 256), dim3(256), 0, stream,
                       Win, Wh, WBh, WBl);
    hipLaunchKernelGGL(gru_persist, dim3(NBLK), dim3(BLOCK_T), 0, stream,
                       x, bin, WBh, WBl, out, hx2, flags);
}

// Round 14
// 2534.660 us; speedup vs baseline: 2.6636x; 1.0086x over previous
//
#include <hip/hip_runtime.h>
#include <math.h>

#define D_IN   512
#define HID    1024
#define SEQ    512
#define NBATCH 64
#define K3     3072
#define KTOT   1536
#define WB_ELEMS (K3 * KTOT)
#define NBLK   256
#define BLOCK_T 768   // 12 waves: 0-7 h-part (fp16, K=128 each), 8-11 x-part (bf16, K=128)

typedef __attribute__((ext_vector_type(8))) short short8;
typedef __attribute__((ext_vector_type(4))) float f32x4;
typedef __attribute__((ext_vector_type(4))) unsigned u32x4;
typedef _Float16 half8 __attribute__((ext_vector_type(8)));

#define MFMA_BF16(a, b, c) __builtin_amdgcn_mfma_f32_16x16x32_bf16((a), (b), (c), 0, 0, 0)
#define MFMA_F16(a, b, c)  __builtin_amdgcn_mfma_f32_16x16x32_f16((a), (b), (c), 0, 0, 0)

// ---------------- build fused transposed weight planes ----------------
// [col 0..3071][k 0..1535]; k<512 (x-part): bf16 hi/lo bits; k>=512 (h-part): fp16 hi/lo bits.
__global__ __launch_bounds__(256) void build_wt(const float* __restrict__ Win,
                                                const float* __restrict__ Wh,
                                                unsigned short* __restrict__ WBh,
                                                unsigned short* __restrict__ WBl) {
    int idx = blockIdx.x * 256 + threadIdx.x;
    if (idx >= WB_ELEMS) return;
    int k   = idx % KTOT;
    int col = idx / KTOT;
    float v = (k < D_IN) ? Win[(size_t)k * K3 + col]
                         : Wh[(size_t)(k - D_IN) * K3 + col];
    unsigned short hb, lb;
    if (k < D_IN) {
        __bf16 h = (__bf16)v;
        hb = __builtin_bit_cast(unsigned short, h);
        lb = __builtin_bit_cast(unsigned short, (__bf16)(v - (float)h));
    } else {
        _Float16 h = (_Float16)v;
        hb = __builtin_bit_cast(unsigned short, h);
        lb = __builtin_bit_cast(unsigned short, (_Float16)(v - (float)h));
    }
    WBh[idx] = hb;
    WBl[idx] = lb;
}

__device__ __forceinline__ void cvt8(const f32x4& v0, const f32x4& v1,
                                     short8& ahi, short8& alo) {
    float af[8] = {v0[0], v0[1], v0[2], v0[3], v1[0], v1[1], v1[2], v1[3]};
    #pragma unroll
    for (int j = 0; j < 8; ++j) {
        __bf16 hb = (__bf16)af[j];
        __bf16 lb = (__bf16)(af[j] - (float)hb);
        ahi[j] = __builtin_bit_cast(short, hb);
        alo[j] = __builtin_bit_cast(short, lb);
    }
}

// ---------------- persistent GRU: fragment-order coalesced h exchange ----------------
// hx3[slot][mq][w] = contiguous 4KB wave-block holding h[t] (fp16, NO tags) in
// EXACT f16-MFMA A-fragment order: half idx = ((si*4+g)*16 + b)*8 + e, where
// lane l = (g=l>>4, b=l&15), si = 32-k subtile, e = k&7. Consumer wave issues
// FOUR dwordx4 at base + l*16 (+{0,1024,2048,3072}) -> each inst reads 1KB
// CONTIGUOUS (~16 lines vs 64 scattered in round 13) and lands directly as
// half8 fragments (no unpack).
// Ordering: producer epilogue wave stores its 64 fp16 halves (sc0sc1), DRAINS
// (vmcnt 0 -> data at L3), THEN stores its flag = t+1 (sc0sc1). Consumer polls
// 32 flags (monotonic >= t), then loads data once. Flag observed => data
// visible (both L3-serialized). Ring-2 WAR proof as round 13: P's step-t+2
// overwrite of slot t&1 is gated (via flag union across its 8 h-waves = all 64
// blocks) on every block's step-t+1 loads having returned.
__global__ __attribute__((amdgpu_waves_per_eu(3, 3)))
__launch_bounds__(BLOCK_T) void gru_persist(
        const float* __restrict__ x, const float* __restrict__ bin,
        const unsigned short* __restrict__ WBh, const unsigned short* __restrict__ WBl,
        float* __restrict__ out, unsigned short* __restrict__ hx3,
        unsigned* __restrict__ flags) {
    __shared__ float red[2][12][3][4][64];   // 72 KB, double-buffered
    float* hall = out + NBATCH * HID;

    const int tid = threadIdx.x;
    const int l   = tid & 63;
    const int w   = tid >> 6;              // 0..11
    const int xcd = blockIdx.x & 7;
    const int j   = blockIdx.x >> 3;
    const int nb  = xcd + 8 * (j >> 2);
    const int mq  = j & 3;
    const int cb  = nb * 16;

    const int m    = mq * 16 + (l & 15);
    const int koff = (l >> 4) * 8;
    const int colz = cb + (l & 15);
    const bool isH = (w < 8);
    const int kbase = isH ? (D_IN + 128 * w) : (128 * (w - 8));

    // consumer flag addrs: producer blocks 8w..8w+7 of my domain, epi-waves 0-3
    const unsigned* fp = flags + ((size_t)mq * 64 + 8 * w + ((l & 31) >> 2)) * 4
                               + (l & 3);

    // ---- one-time weight slice -> registers (h-part fp16 bits, x-part bf16 bits)
    short8 Bh[3][4], Bl[3][4];
    #pragma unroll
    for (int g = 0; g < 3; ++g) {
        #pragma unroll
        for (int s = 0; s < 4; ++s) {
            const size_t o = (size_t)(colz + g * HID) * KTOT + kbase + 32 * s + koff;
            Bh[g][s] = *(const short8*)(WBh + o);
            Bl[g][s] = *(const short8*)(WBl + o);
        }
    }
    #pragma unroll
    for (int g = 0; g < 3; ++g) {
        #pragma unroll
        for (int s = 0; s < 4; ++s) {
            asm volatile("" : "+v"(Bh[g][s]));
            asm volatile("" : "+v"(Bl[g][s]));
        }
    }

    // epilogue constants (waves 0-3)
    const int r2 = tid >> 6;
    const int l2 = tid & 63;
    const int be = mq * 16 + (l2 >> 4) * 4 + r2;   // C layout (m89)
    const int ce = cb + (l2 & 15);
    float bz = 0.f, br = 0.f, bnb = 0.f, hreg = 0.f;
    unsigned* fprod = flags + ((size_t)mq * 64 + nb) * 4 + r2;
    // producer scatter target inside destination wave-block (fragment order)
    const int p_w  = nb >> 3;                         // dest k-slice wave
    const int p_si = (nb & 7) >> 1;                   // 32-k subtile
    const int p_g  = ((nb & 1) << 1) | ((l2 >> 3) & 1);
    const int p_e  = l2 & 7;
    const int p_b  = (l2 >> 4) * 4 + r2;              // be & 15
    const size_t p_off = (size_t)((p_si * 4 + p_g) * 16 + p_b) * 8 + p_e;
    if (tid < 256) {
        bz  = bin[ce];
        br  = bin[HID + ce];
        bnb = bin[2 * HID + ce];
    }
    asm volatile("" : "+v"(bz), "+v"(br), "+v"(bnb));

    for (int t = 0; t < SEQ; ++t) {
        f32x4 aZ = {0.f,0.f,0.f,0.f}, aR = {0.f,0.f,0.f,0.f}, aN = {0.f,0.f,0.f,0.f};

        if (isH) {
            if (t > 0) {
                const unsigned tagexp = (unsigned)t;
                // ---- cheap flag poll (2 cache lines per wave per iter)
                while (true) {
                    unsigned f;
                    asm volatile("global_load_dword %0, %1, off sc0 sc1\n\t"
                                 "s_waitcnt vmcnt(0)"
                                 : "=v"(f) : "v"(fp));
                    if (__all(f >= tagexp)) break;
                    __builtin_amdgcn_s_sleep(1);
                }
                // ---- coalesced data burst: 4x dwordx4, each 1KB contiguous
                const unsigned short* hp = hx3
                    + ((size_t)(((t - 1) & 1) * 4 + mq) * 8 + w) * 2048
                    + (size_t)l * 8;
                u32x4 q0, q1, q2, q3;
                asm volatile(
                    "global_load_dwordx4 %0, %4, off sc0 sc1\n\t"
                    "global_load_dwordx4 %1, %4, off offset:1024 sc0 sc1\n\t"
                    "global_load_dwordx4 %2, %4, off offset:2048 sc0 sc1\n\t"
                    "global_load_dwordx4 %3, %4, off offset:3072 sc0 sc1\n\t"
                    "s_waitcnt vmcnt(0)"
                    : "=&v"(q0), "=&v"(q1), "=&v"(q2), "=&v"(q3)
                    : "v"(hp));
                #define SUBT16(si, q) { \
                    half8 ah = __builtin_bit_cast(half8, (q)); \
                    aZ = MFMA_F16(ah, __builtin_bit_cast(half8, Bh[0][si]), aZ); \
                    aZ = MFMA_F16(ah, __builtin_bit_cast(half8, Bl[0][si]), aZ); \
                    aR = MFMA_F16(ah, __builtin_bit_cast(half8, Bh[1][si]), aR); \
                    aR = MFMA_F16(ah, __builtin_bit_cast(half8, Bl[1][si]), aR); \
                    aN = MFMA_F16(ah, __builtin_bit_cast(half8, Bh[2][si]), aN); \
                    aN = MFMA_F16(ah, __builtin_bit_cast(half8, Bl[2][si]), aN); }
                SUBT16(0, q0)
                SUBT16(1, q1)
                SUBT16(2, q2)
                SUBT16(3, q3)
                #undef SUBT16
            }
        } else {
            const float* xp = x + ((size_t)m * SEQ + t) * D_IN + kbase + koff;
            #pragma unroll
            for (int s = 0; s < 4; ++s) {
                f32x4 v0 = *(const f32x4*)(xp + 32 * s);
                f32x4 v1 = *(const f32x4*)(xp + 32 * s + 4);
                short8 ahi, alo;
                cvt8(v0, v1, ahi, alo);
                aZ = MFMA_BF16(ahi, Bh[0][s], aZ); aZ = MFMA_BF16(ahi, Bl[0][s], aZ);
                aZ = MFMA_BF16(alo, Bh[0][s], aZ);
                aR = MFMA_BF16(ahi, Bh[1][s], aR); aR = MFMA_BF16(ahi, Bl[1][s], aR);
                aR = MFMA_BF16(alo, Bh[1][s], aR);
                aN = MFMA_BF16(ahi, Bh[2][s], aN); aN = MFMA_BF16(ahi, Bl[2][s], aN);
                aN = MFMA_BF16(alo, Bh[2][s], aN);
            }
        }

        const int buf = t & 1;
        #pragma unroll
        for (int r = 0; r < 4; ++r) {
            red[buf][w][0][r][l] = aZ[r];
            red[buf][w][1][r][l] = aR[r];
            red[buf][w][2][r][l] = aN[r];
        }
        __syncthreads();   // red[t] published (single barrier per step)

        if (tid < 256) {
            float sz = 0.f, sr = 0.f, snx = 0.f, snh = 0.f;
            #pragma unroll
            for (int wv = 0; wv < 8; ++wv) {
                sz  += red[buf][wv][0][r2][l2];
                sr  += red[buf][wv][1][r2][l2];
                snh += red[buf][wv][2][r2][l2];
            }
            #pragma unroll
            for (int wv = 8; wv < 12; ++wv) {
                sz  += red[buf][wv][0][r2][l2];
                sr  += red[buf][wv][1][r2][l2];
                snx += red[buf][wv][2][r2][l2];
            }
            float z   = 1.f / (1.f + __expf(-(sz + bz)));
            float rr  = 1.f / (1.f + __expf(-(sr + br)));
            float pre = snx + bnb + rr * snh;
            float e2  = __expf(2.f * pre);
            float n   = 1.f - 2.f / (e2 + 1.f);
            float h   = (1.f - z) * n + z * hreg;
            hreg = h;

            // fragment-order fp16 data store -> drain (data at L3) -> flag
            unsigned hv = (unsigned)__builtin_bit_cast(unsigned short, (_Float16)h);
            unsigned short* hxp = hx3
                + ((size_t)((t & 1) * 4 + mq) * 8 + p_w) * 2048 + p_off;
            asm volatile("global_store_short %0, %1, off sc0 sc1"
                         :: "v"(hxp), "v"(hv) : "memory");
            asm volatile("s_waitcnt vmcnt(0)" ::: "memory");
            if ((tid & 63) == 0) {
                unsigned fv = (unsigned)(t + 1);
                asm volatile("global_store_dword %0, %1, off sc0 sc1"
                             :: "v"(fprod), "v"(fv) : "memory");
            }
            // archival fp32 writes: off critical path, normal cached stores
            hall[((size_t)be * SEQ + t) * HID + ce] = h;
            if (t == SEQ - 1) out[(size_t)be * HID + ce] = h;
        }
    }
}

extern "C" void kernel_launch(void* const* d_in, const int* in_sizes, int n_in,
                              void* d_out, int out_size, void* d_ws, size_t ws_size,
                              hipStream_t stream) {
    const float* x   = (const float*)d_in[0];
    const float* Win = (const float*)d_in[1];
    const float* bin = (const float*)d_in[2];
    const float* Wh  = (const float*)d_in[3];
    float* out = (float*)d_out;

    unsigned short* WBh = (unsigned short*)d_ws;                       // 9.44 MB
    unsigned short* WBl = (unsigned short*)d_ws + (size_t)WB_ELEMS;    // 9.44 MB
    const size_t hx_off = ((size_t)2 * WB_ELEMS * sizeof(unsigned short) + (1u << 20))
                          & ~((size_t)(1u << 20) - 1);                 // 1MB-aligned
    unsigned* flags      = (unsigned*)((char*)d_ws + hx_off);          // 4 KB
    unsigned short* hx3  = (unsigned short*)((char*)d_ws + hx_off + 65536); // 256 KB

    // zero flags every launch (replay-safe; hx3 needs no init - flag-gated)
    hipMemsetAsync(flags, 0, 4096, stream);
    hipLaunchKernelGGL(build_wt, dim3((WB_ELEMS + 255) / 256), dim3(256), 0, stream,
                       Win, Wh, WBh, WBl);
    hipLaunchKernelGGL(gru_persist, dim3(NBLK), dim3(BLOCK_T), 0, stream,
                       x, bin, WBh, WBl, out, hx3, flags);
}

// Round 15
// 2404.602 us; speedup vs baseline: 2.8077x; 1.0541x over previous
//
#include <hip/hip_runtime.h>
#include <math.h>

#define D_IN   512
#define HID    1024
#define SEQ    512
#define NBATCH 64
#define K3     3072
#define KTOT   1536
#define WB_ELEMS (K3 * KTOT)
#define NBLK   256
#define BLOCK_T 768   // 12 waves: 0-7 h-part (fp16, K=128 each), 8-11 x-part (bf16, K=128)

typedef __attribute__((ext_vector_type(8))) short short8;
typedef __attribute__((ext_vector_type(4))) float f32x4;
typedef __attribute__((ext_vector_type(4))) unsigned u32x4;
typedef _Float16 half8 __attribute__((ext_vector_type(8)));

#define MFMA_BF16(a, b, c) __builtin_amdgcn_mfma_f32_16x16x32_bf16((a), (b), (c), 0, 0, 0)
#define MFMA_F16(a, b, c)  __builtin_amdgcn_mfma_f32_16x16x32_f16((a), (b), (c), 0, 0, 0)

// ---------------- build fused transposed weight planes ----------------
// [col 0..3071][k 0..1535]; k<512 (x-part): bf16 hi/lo bits; k>=512 (h-part): fp16 hi/lo bits.
__global__ __launch_bounds__(256) void build_wt(const float* __restrict__ Win,
                                                const float* __restrict__ Wh,
                                                unsigned short* __restrict__ WBh,
                                                unsigned short* __restrict__ WBl) {
    int idx = blockIdx.x * 256 + threadIdx.x;
    if (idx >= WB_ELEMS) return;
    int k   = idx % KTOT;
    int col = idx / KTOT;
    float v = (k < D_IN) ? Win[(size_t)k * K3 + col]
                         : Wh[(size_t)(k - D_IN) * K3 + col];
    unsigned short hb, lb;
    if (k < D_IN) {
        __bf16 h = (__bf16)v;
        hb = __builtin_bit_cast(unsigned short, h);
        lb = __builtin_bit_cast(unsigned short, (__bf16)(v - (float)h));
    } else {
        _Float16 h = (_Float16)v;
        hb = __builtin_bit_cast(unsigned short, h);
        lb = __builtin_bit_cast(unsigned short, (_Float16)(v - (float)h));
    }
    WBh[idx] = hb;
    WBl[idx] = lb;
}

__device__ __forceinline__ void cvt8(const f32x4& v0, const f32x4& v1,
                                     short8& ahi, short8& alo) {
    float af[8] = {v0[0], v0[1], v0[2], v0[3], v1[0], v1[1], v1[2], v1[3]};
    #pragma unroll
    for (int j = 0; j < 8; ++j) {
        __bf16 hb = (__bf16)af[j];
        __bf16 lb = (__bf16)(af[j] - (float)hb);
        ahi[j] = __builtin_bit_cast(short, hb);
        alo[j] = __builtin_bit_cast(short, lb);
    }
}

// ---------------- persistent GRU: fragment-order exchange + streaming consume ----------------
// hx3[slot][mq][w] = contiguous 4KB wave-block holding h[t] (fp16) in EXACT
// f16-MFMA A-fragment order (half idx = ((si*4+g)*16+b)*8+e). Producer wave:
// 64 fp16 stores (sc0sc1) -> vmcnt(0) drain -> flag = t+1 (sc0sc1).
// NEW vs round 14 (skew absorption): subtile si of consumer wave w depends
// ONLY on producer blocks {8w+2si, 8w+2si+1}. Ballot-based streaming loop:
// each iteration re-loads the 32 flags (2 cache lines), computes per-pair
// readiness via __ballot (wave-uniform), and ISSUES subtile si's dwordx4 the
// moment its pair is ready. Loads of early producers overlap the wait for
// slow ones; final vmcnt(0) is register-tied ("+v") so MFMAs can't hoist.
// Ring-2 WAR proof unchanged: P's step-t+2 overwrite of slot t&1 is gated
// (flag union over its 8 h-waves = all 64 blocks) on every block's step-t+1
// loads having returned (loads complete before that block's t+1 flag).
__global__ __attribute__((amdgpu_waves_per_eu(3, 3)))
__launch_bounds__(BLOCK_T) void gru_persist(
        const float* __restrict__ x, const float* __restrict__ bin,
        const unsigned short* __restrict__ WBh, const unsigned short* __restrict__ WBl,
        float* __restrict__ out, unsigned short* __restrict__ hx3,
        unsigned* __restrict__ flags) {
    __shared__ float red[2][12][3][4][64];   // 72 KB, double-buffered
    float* hall = out + NBATCH * HID;

    const int tid = threadIdx.x;
    const int l   = tid & 63;
    const int w   = tid >> 6;              // 0..11
    const int xcd = blockIdx.x & 7;
    const int j   = blockIdx.x >> 3;
    const int nb  = xcd + 8 * (j >> 2);
    const int mq  = j & 3;
    const int cb  = nb * 16;

    const int m    = mq * 16 + (l & 15);
    const int koff = (l >> 4) * 8;
    const int colz = cb + (l & 15);
    const bool isH = (w < 8);
    const int kbase = isH ? (D_IN + 128 * w) : (128 * (w - 8));

    // consumer flag addrs: producer blocks 8w..8w+7 of my domain, epi-waves 0-3
    // lane l reads flag word (l&31): block 8w + ((l&31)>>2), wave (l&3)
    const unsigned* fpal = flags + ((size_t)mq * 64 + 8 * w) * 4 + (l & 31);

    // ---- one-time weight slice -> registers (h-part fp16 bits, x-part bf16 bits)
    short8 Bh[3][4], Bl[3][4];
    #pragma unroll
    for (int g = 0; g < 3; ++g) {
        #pragma unroll
        for (int s = 0; s < 4; ++s) {
            const size_t o = (size_t)(colz + g * HID) * KTOT + kbase + 32 * s + koff;
            Bh[g][s] = *(const short8*)(WBh + o);
            Bl[g][s] = *(const short8*)(WBl + o);
        }
    }
    #pragma unroll
    for (int g = 0; g < 3; ++g) {
        #pragma unroll
        for (int s = 0; s < 4; ++s) {
            asm volatile("" : "+v"(Bh[g][s]));
            asm volatile("" : "+v"(Bl[g][s]));
        }
    }

    // epilogue constants (waves 0-3)
    const int r2 = tid >> 6;
    const int l2 = tid & 63;
    const int be = mq * 16 + (l2 >> 4) * 4 + r2;   // C layout (m89)
    const int ce = cb + (l2 & 15);
    float bz = 0.f, br = 0.f, bnb = 0.f, hreg = 0.f;
    unsigned* fprod = flags + ((size_t)mq * 64 + nb) * 4 + r2;
    // producer scatter target inside destination wave-block (fragment order)
    const int p_w  = nb >> 3;                         // dest k-slice wave
    const int p_si = (nb & 7) >> 1;                   // 32-k subtile
    const int p_g  = ((nb & 1) << 1) | ((l2 >> 3) & 1);
    const int p_e  = l2 & 7;
    const int p_b  = (l2 >> 4) * 4 + r2;              // be & 15
    const size_t p_off = (size_t)((p_si * 4 + p_g) * 16 + p_b) * 8 + p_e;
    if (tid < 256) {
        bz  = bin[ce];
        br  = bin[HID + ce];
        bnb = bin[2 * HID + ce];
    }
    asm volatile("" : "+v"(bz), "+v"(br), "+v"(bnb));

    for (int t = 0; t < SEQ; ++t) {
        f32x4 aZ = {0.f,0.f,0.f,0.f}, aR = {0.f,0.f,0.f,0.f}, aN = {0.f,0.f,0.f,0.f};

        if (isH) {
            if (t > 0) {
                const unsigned tagexp = (unsigned)t;
                const unsigned short* hp = hx3
                    + ((size_t)(((t - 1) & 1) * 4 + mq) * 8 + w) * 2048
                    + (size_t)l * 8;
                u32x4 q0 = {0,0,0,0}, q1 = {0,0,0,0}, q2 = {0,0,0,0}, q3 = {0,0,0,0};
                unsigned need = 0xFu;   // pending subtile bitmask (wave-uniform)
                while (true) {
                    unsigned f;
                    asm volatile("global_load_dword %0, %1, off sc0 sc1\n\t"
                                 "s_waitcnt vmcnt(0)"
                                 : "=v"(f) : "v"(fpal));
                    unsigned long long rdy = __ballot(f >= tagexp);
                    // pair si ready <=> lanes [8si, 8si+8) all set
                    if ((need & 1u) && (((rdy >> 0)  & 0xFFull) == 0xFFull)) {
                        asm volatile("global_load_dwordx4 %0, %1, off sc0 sc1"
                                     : "=&v"(q0) : "v"(hp));
                        need &= ~1u;
                    }
                    if ((need & 2u) && (((rdy >> 8)  & 0xFFull) == 0xFFull)) {
                        asm volatile("global_load_dwordx4 %0, %1, off offset:1024 sc0 sc1"
                                     : "=&v"(q1) : "v"(hp));
                        need &= ~2u;
                    }
                    if ((need & 4u) && (((rdy >> 16) & 0xFFull) == 0xFFull)) {
                        asm volatile("global_load_dwordx4 %0, %1, off offset:2048 sc0 sc1"
                                     : "=&v"(q2) : "v"(hp));
                        need &= ~4u;
                    }
                    if ((need & 8u) && (((rdy >> 24) & 0xFFull) == 0xFFull)) {
                        asm volatile("global_load_dwordx4 %0, %1, off offset:3072 sc0 sc1"
                                     : "=&v"(q3) : "v"(hp));
                        need &= ~8u;
                    }
                    if (!need) break;
                    __builtin_amdgcn_s_sleep(1);
                }
                // drain all data loads; "+v" ties MFMAs after this wait (rule 18)
                asm volatile("s_waitcnt vmcnt(0)"
                             : "+v"(q0), "+v"(q1), "+v"(q2), "+v"(q3));
                __builtin_amdgcn_sched_barrier(0);
                #define SUBT16(si, q) { \
                    half8 ah = __builtin_bit_cast(half8, (q)); \
                    aZ = MFMA_F16(ah, __builtin_bit_cast(half8, Bh[0][si]), aZ); \
                    aZ = MFMA_F16(ah, __builtin_bit_cast(half8, Bl[0][si]), aZ); \
                    aR = MFMA_F16(ah, __builtin_bit_cast(half8, Bh[1][si]), aR); \
                    aR = MFMA_F16(ah, __builtin_bit_cast(half8, Bl[1][si]), aR); \
                    aN = MFMA_F16(ah, __builtin_bit_cast(half8, Bh[2][si]), aN); \
                    aN = MFMA_F16(ah, __builtin_bit_cast(half8, Bl[2][si]), aN); }
                SUBT16(0, q0)
                SUBT16(1, q1)
                SUBT16(2, q2)
                SUBT16(3, q3)
                #undef SUBT16
            }
        } else {
            const float* xp = x + ((size_t)m * SEQ + t) * D_IN + kbase + koff;
            #pragma unroll
            for (int s = 0; s < 4; ++s) {
                f32x4 v0 = *(const f32x4*)(xp + 32 * s);
                f32x4 v1 = *(const f32x4*)(xp + 32 * s + 4);
                short8 ahi, alo;
                cvt8(v0, v1, ahi, alo);
                aZ = MFMA_BF16(ahi, Bh[0][s], aZ); aZ = MFMA_BF16(ahi, Bl[0][s], aZ);
                aZ = MFMA_BF16(alo, Bh[0][s], aZ);
                aR = MFMA_BF16(ahi, Bh[1][s], aR); aR = MFMA_BF16(ahi, Bl[1][s], aR);
                aR = MFMA_BF16(alo, Bh[1][s], aR);
                aN = MFMA_BF16(ahi, Bh[2][s], aN); aN = MFMA_BF16(ahi, Bl[2][s], aN);
                aN = MFMA_BF16(alo, Bh[2][s], aN);
            }
        }

        const int buf = t & 1;
        #pragma unroll
        for (int r = 0; r < 4; ++r) {
            red[buf][w][0][r][l] = aZ[r];
            red[buf][w][1][r][l] = aR[r];
            red[buf][w][2][r][l] = aN[r];
        }
        __syncthreads();   // red[t] published (single barrier per step)

        if (tid < 256) {
            float sz = 0.f, sr = 0.f, snx = 0.f, snh = 0.f;
            #pragma unroll
            for (int wv = 0; wv < 8; ++wv) {
                sz  += red[buf][wv][0][r2][l2];
                sr  += red[buf][wv][1][r2][l2];
                snh += red[buf][wv][2][r2][l2];
            }
            #pragma unroll
            for (int wv = 8; wv < 12; ++wv) {
                sz  += red[buf][wv][0][r2][l2];
                sr  += red[buf][wv][1][r2][l2];
                snx += red[buf][wv][2][r2][l2];
            }
            float z   = 1.f / (1.f + __expf(-(sz + bz)));
            float rr  = 1.f / (1.f + __expf(-(sr + br)));
            float pre = snx + bnb + rr * snh;
            float e2  = __expf(2.f * pre);
            float n   = 1.f - 2.f / (e2 + 1.f);
            float h   = (1.f - z) * n + z * hreg;
            hreg = h;

            // fragment-order fp16 data store -> drain (data at L3) -> flag
            unsigned hv = (unsigned)__builtin_bit_cast(unsigned short, (_Float16)h);
            unsigned short* hxp = hx3
                + ((size_t)((t & 1) * 4 + mq) * 8 + p_w) * 2048 + p_off;
            asm volatile("global_store_short %0, %1, off sc0 sc1"
                         :: "v"(hxp), "v"(hv) : "memory");
            asm volatile("s_waitcnt vmcnt(0)" ::: "memory");
            if ((tid & 63) == 0) {
                unsigned fv = (unsigned)(t + 1);
                asm volatile("global_store_dword %0, %1, off sc0 sc1"
                             :: "v"(fprod), "v"(fv) : "memory");
            }
            // archival fp32 writes: off critical path, normal cached stores
            hall[((size_t)be * SEQ + t) * HID + ce] = h;
            if (t == SEQ - 1) out[(size_t)be * HID + ce] = h;
        }
    }
}

extern "C" void kernel_launch(void* const* d_in, const int* in_sizes, int n_in,
                              void* d_out, int out_size, void* d_ws, size_t ws_size,
                              hipStream_t stream) {
    const float* x   = (const float*)d_in[0];
    const float* Win = (const float*)d_in[1];
    const float* bin = (const float*)d_in[2];
    const float* Wh  = (const float*)d_in[3];
    float* out = (float*)d_out;

    unsigned short* WBh = (unsigned short*)d_ws;                       // 9.44 MB
    unsigned short* WBl = (unsigned short*)d_ws + (size_t)WB_ELEMS;    // 9.44 MB
    const size_t hx_off = ((size_t)2 * WB_ELEMS * sizeof(unsigned short) + (1u << 20))
                          & ~((size_t)(1u << 20) - 1);                 // 1MB-aligned
    unsigned* flags      = (unsigned*)((char*)d_ws + hx_off);          // 4 KB
    unsigned short* hx3  = (unsigned short*)((char*)d_ws + hx_off + 65536); // 256 KB

    // zero flags every launch (replay-safe; hx3 needs no init - flag-gated)
    hipMemsetAsync(flags, 0, 4096, stream);
    hipLaunchKernelGGL(build_wt, dim3((WB_ELEMS + 255) / 256), dim3(256), 0, stream,
                       Win, Wh, WBh, WBl);
    hipLaunchKernelGGL(gru_persist, dim3(NBLK), dim3(BLOCK_T), 0, stream,
                       x, bin, WBh, WBl, out, hx3, flags);
}